// Round 2
// baseline (151.650 us; speedup 1.0000x reference)
//
#include <hip/hip_runtime.h>
#include <hip/hip_cooperative_groups.h>

namespace cg = cooperative_groups;

#define L_SEQ 2048
#define D_DIM 768
#define N_ST 16
#define NB 4
#define NJ 33            // 16 B + 16 C + 1 s1 (logical)
#define BCS 48           // padded row stride (192 B)
#define NROWS (NB * L_SEQ)          // 8192
#define PROJ_ELEMS (NROWS * NJ)     // 270336
#define DN (D_DIM * N_ST)           // 12288

// chunked-scan geometry: one cooperative grid of GS blocks does everything
#define NCC 64                      // chunks per sequence
#define LCC 32                      // timesteps per chunk (NCC*LCC = L_SEQ)
#define GS  768                     // 3 * NCC * NB = exactly 3 blocks/CU
#define SEGC 4                      // combine: segments per sequence
#define SCC 16                      // combine: chunks per segment (SEGC*SCC = NCC)

// proj GEMM tiling (unchanged, verified)
#define DSPLIT 8
#define DSEG (D_DIM / DSPLIT)       // 96
#define DK 32
#define NCHUNK (DSEG / DK)          // 3
#define RB 128
#define XST 132
#define WST 64

typedef float v2f __attribute__((ext_vector_type(2)));

__device__ __forceinline__ float fast_exp2(float x) {
#if __has_builtin(__builtin_amdgcn_exp2f)
  return __builtin_amdgcn_exp2f(x);
#else
  return __expf(x * 0.69314718055994531f);
#endif
}

__device__ __forceinline__ float softplus_f(float v) {
  float e = fast_exp2(v * 1.44269504088896f);
  float l = __log2f(1.0f + e) * 0.69314718055994531f;
  return (v > 15.0f) ? v : l;
}

__device__ __forceinline__ void pow_tree2(float e1, v2f pw2[8]) {
  float e2s = e1 * e1;
  float e4s = e2s * e2s;
  float e8s = e4s * e4s;
  v2f s2 = {e2s, e2s}, s4 = {e4s, e4s}, s8 = {e8s, e8s};
  pw2[0] = (v2f){e1, e2s};
  pw2[1] = pw2[0] * s2;
  pw2[2] = pw2[0] * s4;
  pw2[3] = pw2[1] * s4;
  pw2[4] = pw2[0] * s8;
  pw2[5] = pw2[1] * s8;
  pw2[6] = pw2[2] * s8;
  pw2[7] = pw2[3] * s8;
}

// ---------------------------------------------------------------------------
// Projection GEMM, K-split 8 ways. (Verified; unchanged.)
// ---------------------------------------------------------------------------
__global__ __launch_bounds__(256) void k_proj_gemm(
    const float* __restrict__ x, const float* __restrict__ W_bc,
    const float* __restrict__ W_1, float* __restrict__ PBC) {
  __shared__ float xs_t[DK * XST];
  __shared__ float ws_t[DK * WST];

  const int ds  = blockIdx.x % DSPLIT;
  const int rb0 = (blockIdx.x / DSPLIT) * RB;
  const int dbase = ds * DSEG;
  const int tid = threadIdx.x;
  const int rg = tid & 31;
  const int jg = tid >> 5;

  float acc[4][5];
#pragma unroll
  for (int i = 0; i < 4; ++i)
#pragma unroll
    for (int k = 0; k < 5; ++k) acc[i][k] = 0.0f;

  const int lrow = tid >> 1;
  const int lhalf = (tid & 1) * 16;
  const float* xg_row = x + (size_t)(rb0 + lrow) * D_DIM + dbase + lhalf;

  for (int ch = 0; ch < NCHUNK; ++ch) {
    const int dc = dbase + ch * DK;
    float4 xv[4];
#pragma unroll
    for (int q = 0; q < 4; ++q)
      xv[q] = *(const float4*)(xg_row + ch * DK + q * 4);
    float wv[8];
    int widx[8];
#pragma unroll
    for (int u = 0; u < 8; ++u) {
      int idx = tid + u * 256;
      int dk = idx >> 6, slot = idx & 63;
      int wjg = slot >> 3, wk = slot & 7;
      int j = wjg + 8 * wk;
      float v = 0.0f;
      if (wk < 5) {
        if (j < 32)       v = W_bc[(size_t)j * D_DIM + dc + dk];
        else if (j == 32) v = W_1[dc + dk];
      }
      wv[u] = v; widx[u] = dk * WST + slot;
    }
    __syncthreads();
#pragma unroll
    for (int q = 0; q < 4; ++q) {
      xs_t[(lhalf + q * 4 + 0) * XST + lrow] = xv[q].x;
      xs_t[(lhalf + q * 4 + 1) * XST + lrow] = xv[q].y;
      xs_t[(lhalf + q * 4 + 2) * XST + lrow] = xv[q].z;
      xs_t[(lhalf + q * 4 + 3) * XST + lrow] = xv[q].w;
    }
#pragma unroll
    for (int u = 0; u < 8; ++u) ws_t[widx[u]] = wv[u];
    __syncthreads();
#pragma unroll 8
    for (int dk = 0; dk < DK; ++dk) {
      float4 xr = *(const float4*)&xs_t[dk * XST + rg * 4];
      float4 wr = *(const float4*)&ws_t[dk * WST + jg * 8];
      float w4  = ws_t[dk * WST + jg * 8 + 4];
      float xa[4] = {xr.x, xr.y, xr.z, xr.w};
      float wa[5] = {wr.x, wr.y, wr.z, wr.w, w4};
#pragma unroll
      for (int i = 0; i < 4; ++i)
#pragma unroll
        for (int k = 0; k < 5; ++k)
          acc[i][k] = fmaf(xa[i], wa[k], acc[i][k]);
    }
  }

  float* pb = PBC + (size_t)ds * PROJ_ELEMS;
#pragma unroll
  for (int i = 0; i < 4; ++i) {
    int row = rb0 + rg * 4 + i;
#pragma unroll
    for (int k = 0; k < 5; ++k) {
      int j = jg + 8 * k;
      if (k < 4 || jg == 0) pb[(size_t)row * NJ + j] = acc[i][k];
    }
  }
}

// ---------------------------------------------------------------------------
// Phase bodies (shared by the cooperative mega-kernel and the fallback path)
// ---------------------------------------------------------------------------
__device__ __forceinline__ void phase_reduce(
    const float* __restrict__ PBC, const float* __restrict__ b_bc,
    const float* __restrict__ b_1, float* __restrict__ BC48) {
  const int t0 = blockIdx.x * 256 + threadIdx.x;
  for (int idx = t0; idx < PROJ_ELEMS; idx += GS * 256) {
    const int row = idx / NJ;
    const int j = idx - row * NJ;
    float s = 0.0f;
#pragma unroll
    for (int k = 0; k < DSPLIT; ++k) s += PBC[(size_t)k * PROJ_ELEMS + idx];
    s += (j < 32) ? b_bc[j] : b_1[0];
    BC48[(size_t)row * BCS + j] = s;
  }
}

__device__ __forceinline__ void phase_scan1(
    const float* __restrict__ x, const float* __restrict__ A_log,
    const float* __restrict__ W_d, const float* __restrict__ b_d,
    const float* __restrict__ BC48, float* __restrict__ DS,
    float* __restrict__ H) {
  const int cb = blockIdx.x % 3;
  const int c  = (blockIdx.x / 3) % NCC;
  const int b  = blockIdx.x / (3 * NCC);
  const int d  = cb * 256 + threadIdx.x;

  const float wd = W_d[d], bd = b_d[d];
  float Aln[N_ST];
  {
    const float4* al4 = (const float4*)(A_log + (size_t)d * N_ST);
#pragma unroll
    for (int q = 0; q < 4; ++q) {
      float4 v = al4[q];
      Aln[4*q+0] = -__expf(v.x) * 1.44269504088896f;
      Aln[4*q+1] = -__expf(v.y) * 1.44269504088896f;
      Aln[4*q+2] = -__expf(v.z) * 1.44269504088896f;
      Aln[4*q+3] = -__expf(v.w) * 1.44269504088896f;
    }
  }
  bool geom = true;
#pragma unroll
  for (int n = 1; n < N_ST; ++n) {
    float ref = (float)(n + 1) * Aln[0];
    geom = geom && (fabsf(Aln[n] - ref) <= 1e-4f * fabsf(ref) + 1e-12f);
  }
  const float a0 = Aln[0];

  v2f h2[8];
#pragma unroll
  for (int k = 0; k < 8; ++k) h2[k] = (v2f){0.0f, 0.0f};
  float dsum = 0.0f;

  const int l0 = c * LCC;
  const float* bc = BC48 + (size_t)(b * L_SEQ + l0) * BCS;
  const float* xp = x + (size_t)(b * L_SEQ + l0) * D_DIM + d;

  if (geom) {
#pragma unroll 8
    for (int l = 0; l < LCC; ++l) {
      const float* r = bc + l * BCS;
      float4 B0 = *(const float4*)(r + 0);
      float4 B1 = *(const float4*)(r + 4);
      float4 B2 = *(const float4*)(r + 8);
      float4 B3 = *(const float4*)(r + 12);
      float s1 = r[32];
      float delta = softplus_f(fmaf(s1, wd, bd));
      float xv = xp[(size_t)l * D_DIM];
      float f = delta * xv;
      dsum += delta;
      v2f pw2[8];
      pow_tree2(fast_exp2(a0 * delta), pw2);
      v2f f2 = {f, f};
      h2[0] = pw2[0] * h2[0] + f2 * (v2f){B0.x, B0.y};
      h2[1] = pw2[1] * h2[1] + f2 * (v2f){B0.z, B0.w};
      h2[2] = pw2[2] * h2[2] + f2 * (v2f){B1.x, B1.y};
      h2[3] = pw2[3] * h2[3] + f2 * (v2f){B1.z, B1.w};
      h2[4] = pw2[4] * h2[4] + f2 * (v2f){B2.x, B2.y};
      h2[5] = pw2[5] * h2[5] + f2 * (v2f){B2.z, B2.w};
      h2[6] = pw2[6] * h2[6] + f2 * (v2f){B3.x, B3.y};
      h2[7] = pw2[7] * h2[7] + f2 * (v2f){B3.z, B3.w};
    }
  } else {
#pragma unroll 4
    for (int l = 0; l < LCC; ++l) {
      const float* r = bc + l * BCS;
      float s1 = r[32];
      float delta = softplus_f(fmaf(s1, wd, bd));
      float f = delta * xp[(size_t)l * D_DIM];
      dsum += delta;
#pragma unroll
      for (int k = 0; k < 8; ++k) {
        h2[k].x = fmaf(fast_exp2(delta * Aln[2*k]),   h2[k].x, f * r[2*k]);
        h2[k].y = fmaf(fast_exp2(delta * Aln[2*k+1]), h2[k].y, f * r[2*k+1]);
      }
    }
  }

  DS[((size_t)b * NCC + c) * D_DIM + d] = dsum;
  size_t base = ((size_t)(b * NCC + c) * D_DIM + d) * N_ST;
  float4* H4 = (float4*)(H + base);
#pragma unroll
  for (int q = 0; q < 4; ++q)
    H4[q] = make_float4(h2[2*q].x, h2[2*q].y, h2[2*q+1].x, h2[2*q+1].y);
}

// Parallel segmented inter-chunk combine. Block = 64 sequences (one 64-dn
// stripe), wave j (0..3) owns segment j of SCC=16 chunks. All H accesses:
// 64 consecutive dn per wave -> 256 B coalesced.
__device__ __forceinline__ void phase_combine(
    const float* __restrict__ A_log, const float* __restrict__ DS,
    float* __restrict__ H) {
  __shared__ float Pl[SEGC * 65];
  __shared__ float Hl[SEGC * 65];
  const int b    = blockIdx.x / 192;
  const int dn0  = (blockIdx.x % 192) * 64;
  const int lane = threadIdx.x & 63;
  const int j    = threadIdx.x >> 6;          // segment 0..3 (= wave id)
  const int dn   = dn0 + lane;
  const int d    = dn >> 4;

  const float Aln1 = -__expf(A_log[dn]) * 1.44269504088896f;

  const float* dsp = DS + (size_t)b * NCC * D_DIM + d;
  float* Hp = H + (size_t)b * NCC * DN + dn;

  float p[SCC], ph[SCC];
#pragma unroll
  for (int k = 0; k < SCC; ++k) {
    const int c = j * SCC + k;
    p[k]  = fast_exp2(Aln1 * dsp[(size_t)c * D_DIM]);
    ph[k] = Hp[(size_t)c * DN];
  }

  float Pagg = 1.0f, Hagg = 0.0f;
#pragma unroll
  for (int k = 0; k < SCC; ++k) {
    Hagg = fmaf(p[k], Hagg, ph[k]);
    Pagg *= p[k];
  }

  Pl[j * 65 + lane] = Pagg;
  Hl[j * 65 + lane] = Hagg;
  __syncthreads();

  float h = 0.0f;                              // h0 = 0 globally
  for (int j2 = 0; j2 < j; ++j2)
    h = fmaf(Pl[j2 * 65 + lane], h, Hl[j2 * 65 + lane]);

#pragma unroll
  for (int k = 0; k < SCC; ++k) {
    Hp[(size_t)(j * SCC + k) * DN] = h;        // incoming state
    h = fmaf(p[k], h, ph[k]);
  }
}

__device__ __forceinline__ void phase_scan2(
    const float* __restrict__ x, const float* __restrict__ A_log,
    const float* __restrict__ W_d, const float* __restrict__ b_d,
    const float* __restrict__ BC48, const float* __restrict__ HIN,
    float* __restrict__ out) {
  const int cb = blockIdx.x % 3;
  const int c  = (blockIdx.x / 3) % NCC;
  const int b  = blockIdx.x / (3 * NCC);
  const int d  = cb * 256 + threadIdx.x;

  const float wd = W_d[d], bd = b_d[d];
  float Aln[N_ST];
  {
    const float4* al4 = (const float4*)(A_log + (size_t)d * N_ST);
#pragma unroll
    for (int q = 0; q < 4; ++q) {
      float4 v = al4[q];
      Aln[4*q+0] = -__expf(v.x) * 1.44269504088896f;
      Aln[4*q+1] = -__expf(v.y) * 1.44269504088896f;
      Aln[4*q+2] = -__expf(v.z) * 1.44269504088896f;
      Aln[4*q+3] = -__expf(v.w) * 1.44269504088896f;
    }
  }
  bool geom = true;
#pragma unroll
  for (int n = 1; n < N_ST; ++n) {
    float ref = (float)(n + 1) * Aln[0];
    geom = geom && (fabsf(Aln[n] - ref) <= 1e-4f * fabsf(ref) + 1e-12f);
  }
  const float a0 = Aln[0];

  v2f h2[8];
  {
    size_t base = ((size_t)(b * NCC + c) * D_DIM + d) * N_ST;
    const float4* HIN4 = (const float4*)(HIN + base);
#pragma unroll
    for (int q = 0; q < 4; ++q) {
      float4 v = HIN4[q];
      h2[2*q]   = (v2f){v.x, v.y};
      h2[2*q+1] = (v2f){v.z, v.w};
    }
  }

  const int l0 = c * LCC;
  const float* bc = BC48 + (size_t)(b * L_SEQ + l0) * BCS;
  const float* xp = x + (size_t)(b * L_SEQ + l0) * D_DIM + d;
  float* op = out + (size_t)(b * L_SEQ + l0) * D_DIM + d;

  if (geom) {
#pragma unroll 8
    for (int l = 0; l < LCC; ++l) {
      const float* r = bc + l * BCS;
      float4 B0 = *(const float4*)(r + 0);
      float4 B1 = *(const float4*)(r + 4);
      float4 B2 = *(const float4*)(r + 8);
      float4 B3 = *(const float4*)(r + 12);
      float4 C0 = *(const float4*)(r + 16);
      float4 C1 = *(const float4*)(r + 20);
      float4 C2 = *(const float4*)(r + 24);
      float4 C3 = *(const float4*)(r + 28);
      float s1 = r[32];
      float delta = softplus_f(fmaf(s1, wd, bd));
      float xv = xp[(size_t)l * D_DIM];
      float f = delta * xv;
      v2f pw2[8];
      pow_tree2(fast_exp2(a0 * delta), pw2);
      v2f f2 = {f, f};
      v2f y2 = {0.0f, 0.0f};
      h2[0] = pw2[0] * h2[0] + f2 * (v2f){B0.x, B0.y};  y2 += h2[0] * (v2f){C0.x, C0.y};
      h2[1] = pw2[1] * h2[1] + f2 * (v2f){B0.z, B0.w};  y2 += h2[1] * (v2f){C0.z, C0.w};
      h2[2] = pw2[2] * h2[2] + f2 * (v2f){B1.x, B1.y};  y2 += h2[2] * (v2f){C1.x, C1.y};
      h2[3] = pw2[3] * h2[3] + f2 * (v2f){B1.z, B1.w};  y2 += h2[3] * (v2f){C1.z, C1.w};
      h2[4] = pw2[4] * h2[4] + f2 * (v2f){B2.x, B2.y};  y2 += h2[4] * (v2f){C2.x, C2.y};
      h2[5] = pw2[5] * h2[5] + f2 * (v2f){B2.z, B2.w};  y2 += h2[5] * (v2f){C2.z, C2.w};
      h2[6] = pw2[6] * h2[6] + f2 * (v2f){B3.x, B3.y};  y2 += h2[6] * (v2f){C3.x, C3.y};
      h2[7] = pw2[7] * h2[7] + f2 * (v2f){B3.z, B3.w};  y2 += h2[7] * (v2f){C3.z, C3.w};
      op[(size_t)l * D_DIM] = y2.x + y2.y;
    }
  } else {
#pragma unroll 4
    for (int l = 0; l < LCC; ++l) {
      const float* r = bc + l * BCS;
      float s1 = r[32];
      float delta = softplus_f(fmaf(s1, wd, bd));
      float f = delta * xp[(size_t)l * D_DIM];
      float y = 0.0f;
#pragma unroll
      for (int k = 0; k < 8; ++k) {
        h2[k].x = fmaf(fast_exp2(delta * Aln[2*k]),   h2[k].x, f * r[2*k]);
        h2[k].y = fmaf(fast_exp2(delta * Aln[2*k+1]), h2[k].y, f * r[2*k+1]);
        y = fmaf(h2[k].x, r[16 + 2*k], y);
        y = fmaf(h2[k].y, r[16 + 2*k + 1], y);
      }
      op[(size_t)l * D_DIM] = y;
    }
  }
}

// ---------------------------------------------------------------------------
// Cooperative mega-kernel: reduce -> scan1 -> combine -> scan2, one launch.
// GS=768 blocks = exactly 3 blocks/CU; __launch_bounds__(256,3) caps VGPR at
// 170 so the runtime's co-residency check passes.
// ---------------------------------------------------------------------------
__global__ __launch_bounds__(256, 3) void k_mega(
    const float* __restrict__ x, const float* __restrict__ A_log,
    const float* __restrict__ W_d, const float* __restrict__ b_d,
    const float* __restrict__ PBC, const float* __restrict__ b_bc,
    const float* __restrict__ b_1, float* __restrict__ BC48,
    float* __restrict__ DS, float* __restrict__ H, float* __restrict__ out) {
  cg::grid_group grid = cg::this_grid();
  phase_reduce(PBC, b_bc, b_1, BC48);
  grid.sync();
  phase_scan1(x, A_log, W_d, b_d, BC48, DS, H);
  grid.sync();
  phase_combine(A_log, DS, H);
  grid.sync();
  phase_scan2(x, A_log, W_d, b_d, BC48, H, out);
}

// ---- fallback path (if cooperative launch unavailable): same phases as
// four ordinary kernels on the same 768-block grid ----
__global__ __launch_bounds__(256) void k_reduce_f(
    const float* __restrict__ PBC, const float* __restrict__ b_bc,
    const float* __restrict__ b_1, float* __restrict__ BC48) {
  phase_reduce(PBC, b_bc, b_1, BC48);
}
__global__ __launch_bounds__(256, 3) void k_scan1_f(
    const float* __restrict__ x, const float* __restrict__ A_log,
    const float* __restrict__ W_d, const float* __restrict__ b_d,
    const float* __restrict__ BC48, float* __restrict__ DS,
    float* __restrict__ H) {
  phase_scan1(x, A_log, W_d, b_d, BC48, DS, H);
}
__global__ __launch_bounds__(256) void k_combine_f(
    const float* __restrict__ A_log, const float* __restrict__ DS,
    float* __restrict__ H) {
  phase_combine(A_log, DS, H);
}
__global__ __launch_bounds__(256, 3) void k_scan2_f(
    const float* __restrict__ x, const float* __restrict__ A_log,
    const float* __restrict__ W_d, const float* __restrict__ b_d,
    const float* __restrict__ BC48, const float* __restrict__ HIN,
    float* __restrict__ out) {
  phase_scan2(x, A_log, W_d, b_d, BC48, HIN, out);
}

// ---------------------------------------------------------------------------
extern "C" void kernel_launch(void* const* d_in, const int* in_sizes, int n_in,
                              void* d_out, int out_size, void* d_ws, size_t ws_size,
                              hipStream_t stream) {
  const float* x     = (const float*)d_in[0];
  const float* A_log = (const float*)d_in[1];
  const float* W_bc  = (const float*)d_in[2];
  const float* b_bc  = (const float*)d_in[3];
  const float* W_1   = (const float*)d_in[4];
  const float* b_1   = (const float*)d_in[5];
  const float* W_d   = (const float*)d_in[6];
  const float* b_d   = (const float*)d_in[7];
  float* out = (float*)d_out;
  float* ws  = (float*)d_ws;

  // ws (floats): BC48 393216 | PBC 2162688 | DS 196608 | H 3145728  (~23.6 MB)
  float* BC48 = ws;
  float* PBC  = BC48 + (size_t)NROWS * BCS;
  float* DSb  = PBC + (size_t)DSPLIT * PROJ_ELEMS;
  float* H    = DSb + (size_t)NB * NCC * D_DIM;

  k_proj_gemm<<<(NROWS / RB) * DSPLIT, 256, 0, stream>>>(x, W_bc, W_1, PBC);

  static int coop = -1;
  if (coop < 0) {
    int dev = 0;
    (void)hipGetDevice(&dev);
    int v = 0;
    (void)hipDeviceGetAttribute(&v, hipDeviceAttributeCooperativeLaunch, dev);
    coop = v ? 1 : 0;
  }

  if (coop == 1) {
    void* args[] = {(void*)&x, (void*)&A_log, (void*)&W_d, (void*)&b_d,
                    (void*)&PBC, (void*)&b_bc, (void*)&b_1,
                    (void*)&BC48, (void*)&DSb, (void*)&H, (void*)&out};
    hipError_t e = hipLaunchCooperativeKernel((const void*)k_mega, dim3(GS),
                                              dim3(256), args, 0, stream);
    if (e == hipSuccess) return;
    coop = 0;  // fall through to separate launches
  }

  k_reduce_f<<<GS, 256, 0, stream>>>(PBC, b_bc, b_1, BC48);
  k_scan1_f<<<GS, 256, 0, stream>>>(x, A_log, W_d, b_d, BC48, DSb, H);
  k_combine_f<<<GS, 256, 0, stream>>>(A_log, DSb, H);
  k_scan2_f<<<GS, 256, 0, stream>>>(x, A_log, W_d, b_d, BC48, H, out);
}

// Round 3
// 150.366 us; speedup vs baseline: 1.0085x; 1.0085x over previous
//
#include <hip/hip_runtime.h>
#include <hip/hip_cooperative_groups.h>

namespace cg = cooperative_groups;

#define L_SEQ 2048
#define D_DIM 768
#define N_ST 16
#define NB 4
#define NJ 33            // 16 B + 16 C + 1 s1 (logical)
#define BCS 48           // padded row stride (192 B)
#define NROWS (NB * L_SEQ)          // 8192
#define PROJ_ELEMS (NROWS * NJ)     // 270336
#define DN (D_DIM * N_ST)           // 12288

// chunked-scan geometry
#define NCC 64                      // chunks per sequence
#define LCC 32                      // timesteps per chunk
#define GS  768                     // 3 * NCC * NB = exactly 3 blocks/CU
#define SEGC 4                      // combine: segments per sequence
#define SCC 16                      // combine: chunks per segment

// proj GEMM tiling (verified, unchanged)
#define DSPLIT 8
#define DSEG (D_DIM / DSPLIT)       // 96
#define DK 32
#define NCHUNK (DSEG / DK)          // 3
#define RB 128
#define XST 132
#define WST 64

typedef float v2f __attribute__((ext_vector_type(2)));

__device__ __forceinline__ float fast_exp2(float x) {
#if __has_builtin(__builtin_amdgcn_exp2f)
  return __builtin_amdgcn_exp2f(x);
#else
  return __expf(x * 0.69314718055994531f);
#endif
}

__device__ __forceinline__ float softplus_f(float v) {
  float e = fast_exp2(v * 1.44269504088896f);
  float l = __log2f(1.0f + e) * 0.69314718055994531f;
  return (v > 15.0f) ? v : l;
}

__device__ __forceinline__ void pow_tree2(float e1, v2f pw2[8]) {
  float e2s = e1 * e1;
  float e4s = e2s * e2s;
  float e8s = e4s * e4s;
  v2f s2 = {e2s, e2s}, s4 = {e4s, e4s}, s8 = {e8s, e8s};
  pw2[0] = (v2f){e1, e2s};
  pw2[1] = pw2[0] * s2;
  pw2[2] = pw2[0] * s4;
  pw2[3] = pw2[1] * s4;
  pw2[4] = pw2[0] * s8;
  pw2[5] = pw2[1] * s8;
  pw2[6] = pw2[2] * s8;
  pw2[7] = pw2[3] * s8;
}

// ---------------------------------------------------------------------------
// Projection GEMM, K-split 8 ways. (Verified; unchanged.)
// ---------------------------------------------------------------------------
__global__ __launch_bounds__(256) void k_proj_gemm(
    const float* __restrict__ x, const float* __restrict__ W_bc,
    const float* __restrict__ W_1, float* __restrict__ PBC) {
  __shared__ float xs_t[DK * XST];
  __shared__ float ws_t[DK * WST];

  const int ds  = blockIdx.x % DSPLIT;
  const int rb0 = (blockIdx.x / DSPLIT) * RB;
  const int dbase = ds * DSEG;
  const int tid = threadIdx.x;
  const int rg = tid & 31;
  const int jg = tid >> 5;

  float acc[4][5];
#pragma unroll
  for (int i = 0; i < 4; ++i)
#pragma unroll
    for (int k = 0; k < 5; ++k) acc[i][k] = 0.0f;

  const int lrow = tid >> 1;
  const int lhalf = (tid & 1) * 16;
  const float* xg_row = x + (size_t)(rb0 + lrow) * D_DIM + dbase + lhalf;

  for (int ch = 0; ch < NCHUNK; ++ch) {
    const int dc = dbase + ch * DK;
    float4 xv[4];
#pragma unroll
    for (int q = 0; q < 4; ++q)
      xv[q] = *(const float4*)(xg_row + ch * DK + q * 4);
    float wv[8];
    int widx[8];
#pragma unroll
    for (int u = 0; u < 8; ++u) {
      int idx = tid + u * 256;
      int dk = idx >> 6, slot = idx & 63;
      int wjg = slot >> 3, wk = slot & 7;
      int j = wjg + 8 * wk;
      float v = 0.0f;
      if (wk < 5) {
        if (j < 32)       v = W_bc[(size_t)j * D_DIM + dc + dk];
        else if (j == 32) v = W_1[dc + dk];
      }
      wv[u] = v; widx[u] = dk * WST + slot;
    }
    __syncthreads();
#pragma unroll
    for (int q = 0; q < 4; ++q) {
      xs_t[(lhalf + q * 4 + 0) * XST + lrow] = xv[q].x;
      xs_t[(lhalf + q * 4 + 1) * XST + lrow] = xv[q].y;
      xs_t[(lhalf + q * 4 + 2) * XST + lrow] = xv[q].z;
      xs_t[(lhalf + q * 4 + 3) * XST + lrow] = xv[q].w;
    }
#pragma unroll
    for (int u = 0; u < 8; ++u) ws_t[widx[u]] = wv[u];
    __syncthreads();
#pragma unroll 8
    for (int dk = 0; dk < DK; ++dk) {
      float4 xr = *(const float4*)&xs_t[dk * XST + rg * 4];
      float4 wr = *(const float4*)&ws_t[dk * WST + jg * 8];
      float w4  = ws_t[dk * WST + jg * 8 + 4];
      float xa[4] = {xr.x, xr.y, xr.z, xr.w};
      float wa[5] = {wr.x, wr.y, wr.z, wr.w, w4};
#pragma unroll
      for (int i = 0; i < 4; ++i)
#pragma unroll
        for (int k = 0; k < 5; ++k)
          acc[i][k] = fmaf(xa[i], wa[k], acc[i][k]);
    }
  }

  float* pb = PBC + (size_t)ds * PROJ_ELEMS;
#pragma unroll
  for (int i = 0; i < 4; ++i) {
    int row = rb0 + rg * 4 + i;
#pragma unroll
    for (int k = 0; k < 5; ++k) {
      int j = jg + 8 * k;
      if (k < 4 || jg == 0) pb[(size_t)row * NJ + j] = acc[i][k];
    }
  }
}

// Sum K-split partials + bias -> padded BC48 rows.
__global__ __launch_bounds__(256) void k_proj_reduce(
    const float* __restrict__ PBC, const float* __restrict__ b_bc,
    const float* __restrict__ b_1, float* __restrict__ BC48) {
  const int idx = blockIdx.x * 256 + threadIdx.x;   // < PROJ_ELEMS
  const int row = idx / NJ;
  const int j = idx - row * NJ;
  float s = 0.0f;
#pragma unroll
  for (int k = 0; k < DSPLIT; ++k) s += PBC[(size_t)k * PROJ_ELEMS + idx];
  s += (j < 32) ? b_bc[j] : b_1[0];
  BC48[(size_t)row * BCS + j] = s;
}

// ---------------------------------------------------------------------------
// Shared phase bodies (combine used by both paths; scan1/scan2 for fallback)
// ---------------------------------------------------------------------------
__device__ __forceinline__ void phase_combine(
    const float* __restrict__ A_log, const float* __restrict__ DS,
    float* __restrict__ H) {
  __shared__ float Pl[SEGC * 65];
  __shared__ float Hl[SEGC * 65];
  const int b    = blockIdx.x / 192;
  const int dn0  = (blockIdx.x % 192) * 64;
  const int lane = threadIdx.x & 63;
  const int j    = threadIdx.x >> 6;          // segment 0..3 (= wave id)
  const int dn   = dn0 + lane;
  const int d    = dn >> 4;

  const float Aln1 = -__expf(A_log[dn]) * 1.44269504088896f;

  const float* dsp = DS + (size_t)b * NCC * D_DIM + d;
  float* Hp = H + (size_t)b * NCC * DN + dn;

  float p[SCC], ph[SCC];
#pragma unroll
  for (int k = 0; k < SCC; ++k) {
    const int c = j * SCC + k;
    p[k]  = fast_exp2(Aln1 * dsp[(size_t)c * D_DIM]);
    ph[k] = Hp[(size_t)c * DN];
  }

  float Pagg = 1.0f, Hagg = 0.0f;
#pragma unroll
  for (int k = 0; k < SCC; ++k) {
    Hagg = fmaf(p[k], Hagg, ph[k]);
    Pagg *= p[k];
  }

  Pl[j * 65 + lane] = Pagg;
  Hl[j * 65 + lane] = Hagg;
  __syncthreads();

  float h = 0.0f;                              // h0 = 0 globally
  for (int j2 = 0; j2 < j; ++j2)
    h = fmaf(Pl[j2 * 65 + lane], h, Hl[j2 * 65 + lane]);

#pragma unroll
  for (int k = 0; k < SCC; ++k) {
    Hp[(size_t)(j * SCC + k) * DN] = h;        // incoming state
    h = fmaf(p[k], h, ph[k]);
  }
}

__device__ __forceinline__ void phase_scan1(
    const float* __restrict__ x, const float* __restrict__ A_log,
    const float* __restrict__ W_d, const float* __restrict__ b_d,
    const float* __restrict__ BC48, float* __restrict__ DS,
    float* __restrict__ H) {
  const int cb = blockIdx.x % 3;
  const int c  = (blockIdx.x / 3) % NCC;
  const int b  = blockIdx.x / (3 * NCC);
  const int d  = cb * 256 + threadIdx.x;

  const float wd = W_d[d], bd = b_d[d];
  float Aln[N_ST];
  {
    const float4* al4 = (const float4*)(A_log + (size_t)d * N_ST);
#pragma unroll
    for (int q = 0; q < 4; ++q) {
      float4 v = al4[q];
      Aln[4*q+0] = -__expf(v.x) * 1.44269504088896f;
      Aln[4*q+1] = -__expf(v.y) * 1.44269504088896f;
      Aln[4*q+2] = -__expf(v.z) * 1.44269504088896f;
      Aln[4*q+3] = -__expf(v.w) * 1.44269504088896f;
    }
  }
  bool geom = true;
#pragma unroll
  for (int n = 1; n < N_ST; ++n) {
    float ref = (float)(n + 1) * Aln[0];
    geom = geom && (fabsf(Aln[n] - ref) <= 1e-4f * fabsf(ref) + 1e-12f);
  }
  const float a0 = Aln[0];

  v2f h2[8];
#pragma unroll
  for (int k = 0; k < 8; ++k) h2[k] = (v2f){0.0f, 0.0f};
  float dsum = 0.0f;

  const int l0 = c * LCC;
  const float* bc = BC48 + (size_t)(b * L_SEQ + l0) * BCS;
  const float* xp = x + (size_t)(b * L_SEQ + l0) * D_DIM + d;

  if (geom) {
#pragma unroll 8
    for (int l = 0; l < LCC; ++l) {
      const float* r = bc + l * BCS;
      float4 B0 = *(const float4*)(r + 0);
      float4 B1 = *(const float4*)(r + 4);
      float4 B2 = *(const float4*)(r + 8);
      float4 B3 = *(const float4*)(r + 12);
      float s1 = r[32];
      float delta = softplus_f(fmaf(s1, wd, bd));
      float xv = xp[(size_t)l * D_DIM];
      float f = delta * xv;
      dsum += delta;
      v2f pw2[8];
      pow_tree2(fast_exp2(a0 * delta), pw2);
      v2f f2 = {f, f};
      h2[0] = pw2[0] * h2[0] + f2 * (v2f){B0.x, B0.y};
      h2[1] = pw2[1] * h2[1] + f2 * (v2f){B0.z, B0.w};
      h2[2] = pw2[2] * h2[2] + f2 * (v2f){B1.x, B1.y};
      h2[3] = pw2[3] * h2[3] + f2 * (v2f){B1.z, B1.w};
      h2[4] = pw2[4] * h2[4] + f2 * (v2f){B2.x, B2.y};
      h2[5] = pw2[5] * h2[5] + f2 * (v2f){B2.z, B2.w};
      h2[6] = pw2[6] * h2[6] + f2 * (v2f){B3.x, B3.y};
      h2[7] = pw2[7] * h2[7] + f2 * (v2f){B3.z, B3.w};
    }
  } else {
#pragma unroll 4
    for (int l = 0; l < LCC; ++l) {
      const float* r = bc + l * BCS;
      float s1 = r[32];
      float delta = softplus_f(fmaf(s1, wd, bd));
      float f = delta * xp[(size_t)l * D_DIM];
      dsum += delta;
#pragma unroll
      for (int k = 0; k < 8; ++k) {
        h2[k].x = fmaf(fast_exp2(delta * Aln[2*k]),   h2[k].x, f * r[2*k]);
        h2[k].y = fmaf(fast_exp2(delta * Aln[2*k+1]), h2[k].y, f * r[2*k+1]);
      }
    }
  }

  DS[((size_t)b * NCC + c) * D_DIM + d] = dsum;
  size_t base = ((size_t)(b * NCC + c) * D_DIM + d) * N_ST;
  float4* H4 = (float4*)(H + base);
#pragma unroll
  for (int q = 0; q < 4; ++q)
    H4[q] = make_float4(h2[2*q].x, h2[2*q].y, h2[2*q+1].x, h2[2*q+1].y);
}

__device__ __forceinline__ void phase_scan2(
    const float* __restrict__ x, const float* __restrict__ A_log,
    const float* __restrict__ W_d, const float* __restrict__ b_d,
    const float* __restrict__ BC48, const float* __restrict__ HIN,
    float* __restrict__ out) {
  const int cb = blockIdx.x % 3;
  const int c  = (blockIdx.x / 3) % NCC;
  const int b  = blockIdx.x / (3 * NCC);
  const int d  = cb * 256 + threadIdx.x;

  const float wd = W_d[d], bd = b_d[d];
  float Aln[N_ST];
  {
    const float4* al4 = (const float4*)(A_log + (size_t)d * N_ST);
#pragma unroll
    for (int q = 0; q < 4; ++q) {
      float4 v = al4[q];
      Aln[4*q+0] = -__expf(v.x) * 1.44269504088896f;
      Aln[4*q+1] = -__expf(v.y) * 1.44269504088896f;
      Aln[4*q+2] = -__expf(v.z) * 1.44269504088896f;
      Aln[4*q+3] = -__expf(v.w) * 1.44269504088896f;
    }
  }
  bool geom = true;
#pragma unroll
  for (int n = 1; n < N_ST; ++n) {
    float ref = (float)(n + 1) * Aln[0];
    geom = geom && (fabsf(Aln[n] - ref) <= 1e-4f * fabsf(ref) + 1e-12f);
  }
  const float a0 = Aln[0];

  v2f h2[8];
  {
    size_t base = ((size_t)(b * NCC + c) * D_DIM + d) * N_ST;
    const float4* HIN4 = (const float4*)(HIN + base);
#pragma unroll
    for (int q = 0; q < 4; ++q) {
      float4 v = HIN4[q];
      h2[2*q]   = (v2f){v.x, v.y};
      h2[2*q+1] = (v2f){v.z, v.w};
    }
  }

  const int l0 = c * LCC;
  const float* bc = BC48 + (size_t)(b * L_SEQ + l0) * BCS;
  const float* xp = x + (size_t)(b * L_SEQ + l0) * D_DIM + d;
  float* op = out + (size_t)(b * L_SEQ + l0) * D_DIM + d;

  if (geom) {
#pragma unroll 8
    for (int l = 0; l < LCC; ++l) {
      const float* r = bc + l * BCS;
      float4 B0 = *(const float4*)(r + 0);
      float4 B1 = *(const float4*)(r + 4);
      float4 B2 = *(const float4*)(r + 8);
      float4 B3 = *(const float4*)(r + 12);
      float4 C0 = *(const float4*)(r + 16);
      float4 C1 = *(const float4*)(r + 20);
      float4 C2 = *(const float4*)(r + 24);
      float4 C3 = *(const float4*)(r + 28);
      float s1 = r[32];
      float delta = softplus_f(fmaf(s1, wd, bd));
      float xv = xp[(size_t)l * D_DIM];
      float f = delta * xv;
      v2f pw2[8];
      pow_tree2(fast_exp2(a0 * delta), pw2);
      v2f f2 = {f, f};
      v2f y2 = {0.0f, 0.0f};
      h2[0] = pw2[0] * h2[0] + f2 * (v2f){B0.x, B0.y};  y2 += h2[0] * (v2f){C0.x, C0.y};
      h2[1] = pw2[1] * h2[1] + f2 * (v2f){B0.z, B0.w};  y2 += h2[1] * (v2f){C0.z, C0.w};
      h2[2] = pw2[2] * h2[2] + f2 * (v2f){B1.x, B1.y};  y2 += h2[2] * (v2f){C1.x, C1.y};
      h2[3] = pw2[3] * h2[3] + f2 * (v2f){B1.z, B1.w};  y2 += h2[3] * (v2f){C1.z, C1.w};
      h2[4] = pw2[4] * h2[4] + f2 * (v2f){B2.x, B2.y};  y2 += h2[4] * (v2f){C2.x, C2.y};
      h2[5] = pw2[5] * h2[5] + f2 * (v2f){B2.z, B2.w};  y2 += h2[5] * (v2f){C2.z, C2.w};
      h2[6] = pw2[6] * h2[6] + f2 * (v2f){B3.x, B3.y};  y2 += h2[6] * (v2f){C3.x, C3.y};
      h2[7] = pw2[7] * h2[7] + f2 * (v2f){B3.z, B3.w};  y2 += h2[7] * (v2f){C3.z, C3.w};
      op[(size_t)l * D_DIM] = y2.x + y2.y;
    }
  } else {
#pragma unroll 4
    for (int l = 0; l < LCC; ++l) {
      const float* r = bc + l * BCS;
      float s1 = r[32];
      float delta = softplus_f(fmaf(s1, wd, bd));
      float f = delta * xp[(size_t)l * D_DIM];
      float y = 0.0f;
#pragma unroll
      for (int k = 0; k < 8; ++k) {
        h2[k].x = fmaf(fast_exp2(delta * Aln[2*k]),   h2[k].x, f * r[2*k]);
        h2[k].y = fmaf(fast_exp2(delta * Aln[2*k+1]), h2[k].y, f * r[2*k+1]);
        y = fmaf(h2[k].x, r[16 + 2*k], y);
        y = fmaf(h2[k].y, r[16 + 2*k + 1], y);
      }
      op[(size_t)l * D_DIM] = y;
    }
  }
}

// ---------------------------------------------------------------------------
// Fused single-pass scan (cooperative). Phase A keeps y_local[32] in VGPRs;
// phase C applies the inter-chunk correction y += sum_n C*E^n*h_in using a
// scalar logE recomputed from s1 (geometric A). x and BC-B are read ONCE.
// ---------------------------------------------------------------------------
__global__ __launch_bounds__(256, 3) void k_scan_mega(
    const float* __restrict__ x, const float* __restrict__ A_log,
    const float* __restrict__ W_d, const float* __restrict__ b_d,
    const float* __restrict__ BC48, float* __restrict__ DS,
    float* __restrict__ H, float* __restrict__ out) {
  cg::grid_group grid = cg::this_grid();

  const int cb = blockIdx.x % 3;
  const int c  = (blockIdx.x / 3) % NCC;
  const int b  = blockIdx.x / (3 * NCC);
  const int d  = cb * 256 + threadIdx.x;

  const float wd = W_d[d], bd = b_d[d];
  float Aln[N_ST];
  {
    const float4* al4 = (const float4*)(A_log + (size_t)d * N_ST);
#pragma unroll
    for (int q = 0; q < 4; ++q) {
      float4 v = al4[q];
      Aln[4*q+0] = -__expf(v.x) * 1.44269504088896f;
      Aln[4*q+1] = -__expf(v.y) * 1.44269504088896f;
      Aln[4*q+2] = -__expf(v.z) * 1.44269504088896f;
      Aln[4*q+3] = -__expf(v.w) * 1.44269504088896f;
    }
  }
  bool geom = true;
#pragma unroll
  for (int n = 1; n < N_ST; ++n) {
    float ref = (float)(n + 1) * Aln[0];
    geom = geom && (fabsf(Aln[n] - ref) <= 1e-4f * fabsf(ref) + 1e-12f);
  }
  const float a0 = Aln[0];

  const int l0 = c * LCC;
  const float* bc = BC48 + (size_t)(b * L_SEQ + l0) * BCS;
  const float* xp = x + (size_t)(b * L_SEQ + l0) * D_DIM + d;
  float* op = out + (size_t)(b * L_SEQ + l0) * D_DIM + d;

  // ---------------- phase A: local scan (h0=0), y_local in regs ----------
  float yl[LCC];
  v2f h2[8];
#pragma unroll
  for (int k = 0; k < 8; ++k) h2[k] = (v2f){0.0f, 0.0f};
  float dsum = 0.0f;

  if (geom) {
#pragma unroll
    for (int l = 0; l < LCC; ++l) {
      const float* r = bc + l * BCS;
      float4 B0 = *(const float4*)(r + 0);
      float4 B1 = *(const float4*)(r + 4);
      float4 B2 = *(const float4*)(r + 8);
      float4 B3 = *(const float4*)(r + 12);
      float4 C0 = *(const float4*)(r + 16);
      float4 C1 = *(const float4*)(r + 20);
      float4 C2 = *(const float4*)(r + 24);
      float4 C3 = *(const float4*)(r + 28);
      float s1 = r[32];
      float delta = softplus_f(fmaf(s1, wd, bd));
      float xv = xp[(size_t)l * D_DIM];
      float f = delta * xv;
      dsum += delta;
      v2f pw2[8];
      pow_tree2(fast_exp2(a0 * delta), pw2);
      v2f f2 = {f, f};
      v2f y2 = {0.0f, 0.0f};
      h2[0] = pw2[0] * h2[0] + f2 * (v2f){B0.x, B0.y};  y2 += h2[0] * (v2f){C0.x, C0.y};
      h2[1] = pw2[1] * h2[1] + f2 * (v2f){B0.z, B0.w};  y2 += h2[1] * (v2f){C0.z, C0.w};
      h2[2] = pw2[2] * h2[2] + f2 * (v2f){B1.x, B1.y};  y2 += h2[2] * (v2f){C1.x, C1.y};
      h2[3] = pw2[3] * h2[3] + f2 * (v2f){B1.z, B1.w};  y2 += h2[3] * (v2f){C1.z, C1.w};
      h2[4] = pw2[4] * h2[4] + f2 * (v2f){B2.x, B2.y};  y2 += h2[4] * (v2f){C2.x, C2.y};
      h2[5] = pw2[5] * h2[5] + f2 * (v2f){B2.z, B2.w};  y2 += h2[5] * (v2f){C2.z, C2.w};
      h2[6] = pw2[6] * h2[6] + f2 * (v2f){B3.x, B3.y};  y2 += h2[6] * (v2f){C3.x, C3.y};
      h2[7] = pw2[7] * h2[7] + f2 * (v2f){B3.z, B3.w};  y2 += h2[7] * (v2f){C3.z, C3.w};
      yl[l] = y2.x + y2.y;
    }
  } else {
#pragma unroll 4
    for (int l = 0; l < LCC; ++l) {
      const float* r = bc + l * BCS;
      float s1 = r[32];
      float delta = softplus_f(fmaf(s1, wd, bd));
      float f = delta * xp[(size_t)l * D_DIM];
      dsum += delta;
#pragma unroll
      for (int k = 0; k < 8; ++k) {
        h2[k].x = fmaf(fast_exp2(delta * Aln[2*k]),   h2[k].x, f * r[2*k]);
        h2[k].y = fmaf(fast_exp2(delta * Aln[2*k+1]), h2[k].y, f * r[2*k+1]);
      }
    }
  }

  DS[((size_t)b * NCC + c) * D_DIM + d] = dsum;
  {
    size_t base = ((size_t)(b * NCC + c) * D_DIM + d) * N_ST;
    float4* H4 = (float4*)(H + base);
#pragma unroll
    for (int q = 0; q < 4; ++q)
      H4[q] = make_float4(h2[2*q].x, h2[2*q].y, h2[2*q+1].x, h2[2*q+1].y);
  }

  grid.sync();
  // ---------------- phase B: parallel inter-chunk combine ----------------
  phase_combine(A_log, DS, H);
  grid.sync();

  // ---------------- phase C: correction sweep, write out -----------------
  v2f hin2[8];
  {
    size_t base = ((size_t)(b * NCC + c) * D_DIM + d) * N_ST;
    const float4* HIN4 = (const float4*)(H + base);
#pragma unroll
    for (int q = 0; q < 4; ++q) {
      float4 v = HIN4[q];
      hin2[2*q]   = (v2f){v.x, v.y};
      hin2[2*q+1] = (v2f){v.z, v.w};
    }
  }

  if (geom) {
    float logE = 0.0f;
#pragma unroll
    for (int l = 0; l < LCC; ++l) {
      const float* r = bc + l * BCS;
      float delta = softplus_f(fmaf(r[32], wd, bd));
      logE = fmaf(a0, delta, logE);            // prefix through step l (incl.)
      v2f pw2[8];
      pow_tree2(fast_exp2(logE), pw2);
      float4 C0 = *(const float4*)(r + 16);
      float4 C1 = *(const float4*)(r + 20);
      float4 C2 = *(const float4*)(r + 24);
      float4 C3 = *(const float4*)(r + 28);
      v2f y2 = {0.0f, 0.0f};
      y2 += (hin2[0] * pw2[0]) * (v2f){C0.x, C0.y};
      y2 += (hin2[1] * pw2[1]) * (v2f){C0.z, C0.w};
      y2 += (hin2[2] * pw2[2]) * (v2f){C1.x, C1.y};
      y2 += (hin2[3] * pw2[3]) * (v2f){C1.z, C1.w};
      y2 += (hin2[4] * pw2[4]) * (v2f){C2.x, C2.y};
      y2 += (hin2[5] * pw2[5]) * (v2f){C2.z, C2.w};
      y2 += (hin2[6] * pw2[6]) * (v2f){C3.x, C3.y};
      y2 += (hin2[7] * pw2[7]) * (v2f){C3.z, C3.w};
      op[(size_t)l * D_DIM] = yl[l] + y2.x + y2.y;
    }
  } else {
    // full recompute from incoming state (cold path; data never hits it)
#pragma unroll 4
    for (int l = 0; l < LCC; ++l) {
      const float* r = bc + l * BCS;
      float s1 = r[32];
      float delta = softplus_f(fmaf(s1, wd, bd));
      float f = delta * xp[(size_t)l * D_DIM];
      float y = 0.0f;
#pragma unroll
      for (int k = 0; k < 8; ++k) {
        hin2[k].x = fmaf(fast_exp2(delta * Aln[2*k]),   hin2[k].x, f * r[2*k]);
        hin2[k].y = fmaf(fast_exp2(delta * Aln[2*k+1]), hin2[k].y, f * r[2*k+1]);
        y = fmaf(hin2[k].x, r[16 + 2*k], y);
        y = fmaf(hin2[k].y, r[16 + 2*k + 1], y);
      }
      op[(size_t)l * D_DIM] = y;
    }
  }
}

// ---- fallback kernels (non-cooperative 3-launch path, verified in R2) ----
__global__ __launch_bounds__(256, 3) void k_scan1_f(
    const float* __restrict__ x, const float* __restrict__ A_log,
    const float* __restrict__ W_d, const float* __restrict__ b_d,
    const float* __restrict__ BC48, float* __restrict__ DS,
    float* __restrict__ H) {
  phase_scan1(x, A_log, W_d, b_d, BC48, DS, H);
}
__global__ __launch_bounds__(256) void k_combine_f(
    const float* __restrict__ A_log, const float* __restrict__ DS,
    float* __restrict__ H) {
  phase_combine(A_log, DS, H);
}
__global__ __launch_bounds__(256, 3) void k_scan2_f(
    const float* __restrict__ x, const float* __restrict__ A_log,
    const float* __restrict__ W_d, const float* __restrict__ b_d,
    const float* __restrict__ BC48, const float* __restrict__ HIN,
    float* __restrict__ out) {
  phase_scan2(x, A_log, W_d, b_d, BC48, HIN, out);
}

// ---------------------------------------------------------------------------
extern "C" void kernel_launch(void* const* d_in, const int* in_sizes, int n_in,
                              void* d_out, int out_size, void* d_ws, size_t ws_size,
                              hipStream_t stream) {
  const float* x     = (const float*)d_in[0];
  const float* A_log = (const float*)d_in[1];
  const float* W_bc  = (const float*)d_in[2];
  const float* b_bc  = (const float*)d_in[3];
  const float* W_1   = (const float*)d_in[4];
  const float* b_1   = (const float*)d_in[5];
  const float* W_d   = (const float*)d_in[6];
  const float* b_d   = (const float*)d_in[7];
  float* out = (float*)d_out;
  float* ws  = (float*)d_ws;

  // ws (floats): BC48 393216 | PBC 2162688 | DS 196608 | H 3145728  (~23.6 MB)
  float* BC48 = ws;
  float* PBC  = BC48 + (size_t)NROWS * BCS;
  float* DSb  = PBC + (size_t)DSPLIT * PROJ_ELEMS;
  float* H    = DSb + (size_t)NB * NCC * D_DIM;

  k_proj_gemm<<<(NROWS / RB) * DSPLIT, 256, 0, stream>>>(x, W_bc, W_1, PBC);
  k_proj_reduce<<<(PROJ_ELEMS + 255) / 256, 256, 0, stream>>>(PBC, b_bc, b_1, BC48);

  static int coop = -1;
  if (coop < 0) {
    int dev = 0;
    (void)hipGetDevice(&dev);
    int v = 0;
    (void)hipDeviceGetAttribute(&v, hipDeviceAttributeCooperativeLaunch, dev);
    coop = v ? 1 : 0;
  }

  if (coop == 1) {
    void* args[] = {(void*)&x, (void*)&A_log, (void*)&W_d, (void*)&b_d,
                    (void*)&BC48, (void*)&DSb, (void*)&H, (void*)&out};
    hipError_t e = hipLaunchCooperativeKernel((const void*)k_scan_mega, dim3(GS),
                                              dim3(256), args, 0, stream);
    if (e == hipSuccess) return;
    coop = 0;  // fall through to separate launches
  }

  k_scan1_f<<<GS, 256, 0, stream>>>(x, A_log, W_d, b_d, BC48, DSb, H);
  k_combine_f<<<GS, 256, 0, stream>>>(A_log, DSb, H);
  k_scan2_f<<<GS, 256, 0, stream>>>(x, A_log, W_d, b_d, BC48, H, out);
}